// Round 8
// baseline (287.831 us; speedup 1.0000x reference)
//
#include <hip/hip_runtime.h>
#include <hip/hip_cooperative_groups.h>
#include <hip/hip_bf16.h>
#include <math.h>

namespace cg = cooperative_groups;

// Problem constants (reference: BATCH=2048, D=256, TEMP=0.5)
#define NB        2048
#define TWO_N     4096
#define DIM       256
#define EPS       1e-12f
#define NT1D      (TWO_N / 128)                 // 32 tile rows/cols
#define NTILES    (NT1D * (NT1D + 1) / 2)       // 528 upper-triangle tiles
#define GRID      512                           // cooperative grid (2 blocks/CU by 64KB LDS)

// z storage: FRAGMENT-MAJOR tiled layout (r6). For row R, element e:
//   short_idx = (R>>4)*4096 + (e>>5)*512 + ((e>>3)&3)*128 + (R&15)*8 + (e&7)
// A (row-block RB, K-step s) fragment piece = 1 KB contiguous at
// RB*4096 + s*512; lane l's 16 B at +l*8 shorts.

typedef __attribute__((ext_vector_type(8))) short  bf16x8;   // 8 bf16 = 4 VGPRs
typedef __attribute__((ext_vector_type(4))) float  f32x4;    // MFMA C/D

// ---------------------------------------------------------------------------
// Phase 1 (= old nrm_kernel body): block bid handles pairs bid*4 + wave.
// ---------------------------------------------------------------------------
__device__ __forceinline__ void do_nrm(
    const float* __restrict__ emb_i, const float* __restrict__ emb_j,
    short* __restrict__ zt, float* __restrict__ pos, float* __restrict__ out,
    int bid, int t)
{
    int wave = t >> 6, lane = t & 63;
    int r = bid * 4 + wave;                     // pair index 0..2047
    float4 a = ((const float4*)(emb_i + (size_t)r * DIM))[lane];
    float4 b = ((const float4*)(emb_j + (size_t)r * DIM))[lane];
    float sa = a.x*a.x + a.y*a.y + a.z*a.z + a.w*a.w;
    float sb = b.x*b.x + b.y*b.y + b.z*b.z + b.w*b.w;
    float sd = a.x*b.x + a.y*b.y + a.z*b.z + a.w*b.w;
    #pragma unroll
    for (int off = 32; off >= 1; off >>= 1) {
        sa += __shfl_xor(sa, off, 64);
        sb += __shfl_xor(sb, off, 64);
        sd += __shfl_xor(sd, off, 64);
    }
    float si = 1.0f / fmaxf(sqrtf(sa), EPS);
    float sj = 1.0f / fmaxf(sqrtf(sb), EPS);

    int dst = (r >> 4) * 4096 + (lane >> 3) * 512 + ((lane >> 1) & 3) * 128
            + (r & 15) * 8 + (lane & 1) * 4;

    union { __hip_bfloat16 h[4]; uint2 u; } pk;
    pk.h[0] = __float2bfloat16(a.x * si);
    pk.h[1] = __float2bfloat16(a.y * si);
    pk.h[2] = __float2bfloat16(a.z * si);
    pk.h[3] = __float2bfloat16(a.w * si);
    *(uint2*)(zt + dst) = pk.u;                       // z_i row r
    pk.h[0] = __float2bfloat16(b.x * sj);
    pk.h[1] = __float2bfloat16(b.y * sj);
    pk.h[2] = __float2bfloat16(b.z * sj);
    pk.h[3] = __float2bfloat16(b.w * sj);
    *(uint2*)(zt + dst + 128 * 4096) = pk.u;          // z_j row r+2048

    if (lane == 0) pos[r] = sd * si * sj;
    if (bid == 0 && t == 0) out[0] = 0.0f;            // loss accumulator
}

// ---------------------------------------------------------------------------
// Phase 2 (= old simexp_kernel body, r7 LDS-staged version), one tile `id`.
// ---------------------------------------------------------------------------
#define MFMA1(Av, Bv, m, n) \
    acc[m][n] = __builtin_amdgcn_mfma_f32_16x16x32_bf16(Av, Bv, acc[m][n], 0, 0, 0);

#define MFMA_ROW(Av, B0v, B1v, B2v, B3v, m) \
    MFMA1(Av, B0v, m, 0) MFMA1(Av, B1v, m, 1) \
    MFMA1(Av, B2v, m, 2) MFMA1(Av, B3v, m, 3)

#define MMSTEP(A0v, A1v, A2v, A3v, B0v, B1v, B2v, B3v) \
    MFMA_ROW(A0v, B0v, B1v, B2v, B3v, 0) \
    MFMA_ROW(A1v, B0v, B1v, B2v, B3v, 1) \
    MFMA_ROW(A2v, B0v, B1v, B2v, B3v, 2) \
    MFMA_ROW(A3v, B0v, B1v, B2v, B3v, 3)

#define SB __builtin_amdgcn_sched_barrier(0);

#define SLD(c) \
    G0 = *(const bf16x8*)(stg_base + 0 * 4096 + (2*(c)+0) * 512); \
    G1 = *(const bf16x8*)(stg_base + 0 * 4096 + (2*(c)+1) * 512); \
    G2 = *(const bf16x8*)(stg_base + 1 * 4096 + (2*(c)+0) * 512); \
    G3 = *(const bf16x8*)(stg_base + 1 * 4096 + (2*(c)+1) * 512); \
    G4 = *(const bf16x8*)(stg_base + 2 * 4096 + (2*(c)+0) * 512); \
    G5 = *(const bf16x8*)(stg_base + 2 * 4096 + (2*(c)+1) * 512); \
    G6 = *(const bf16x8*)(stg_base + 3 * 4096 + (2*(c)+0) * 512); \
    G7 = *(const bf16x8*)(stg_base + 3 * 4096 + (2*(c)+1) * 512);

#define DSW(bs) \
    *(bf16x8*)&lds[(bs)*16384 + (p0+0)*512 + l8] = G0; \
    *(bf16x8*)&lds[(bs)*16384 + (p0+1)*512 + l8] = G1; \
    *(bf16x8*)&lds[(bs)*16384 + (p0+2)*512 + l8] = G2; \
    *(bf16x8*)&lds[(bs)*16384 + (p0+3)*512 + l8] = G3; \
    *(bf16x8*)&lds[(bs)*16384 + (p0+4)*512 + l8] = G4; \
    *(bf16x8*)&lds[(bs)*16384 + (p0+5)*512 + l8] = G5; \
    *(bf16x8*)&lds[(bs)*16384 + (p0+6)*512 + l8] = G6; \
    *(bf16x8*)&lds[(bs)*16384 + (p0+7)*512 + l8] = G7;

#define CSTEP(bs, sl) \
    { \
        bf16x8 fa0 = *(const bf16x8*)&lds[(bs)*16384 + ((wm4+0)*2+(sl))*512 + l8]; \
        bf16x8 fa1 = *(const bf16x8*)&lds[(bs)*16384 + ((wm4+1)*2+(sl))*512 + l8]; \
        bf16x8 fa2 = *(const bf16x8*)&lds[(bs)*16384 + ((wm4+2)*2+(sl))*512 + l8]; \
        bf16x8 fa3 = *(const bf16x8*)&lds[(bs)*16384 + ((wm4+3)*2+(sl))*512 + l8]; \
        bf16x8 fb0 = *(const bf16x8*)&lds[(bs)*16384 + 8192 + ((wn4+0)*2+(sl))*512 + l8]; \
        bf16x8 fb1 = *(const bf16x8*)&lds[(bs)*16384 + 8192 + ((wn4+1)*2+(sl))*512 + l8]; \
        bf16x8 fb2 = *(const bf16x8*)&lds[(bs)*16384 + 8192 + ((wn4+2)*2+(sl))*512 + l8]; \
        bf16x8 fb3 = *(const bf16x8*)&lds[(bs)*16384 + 8192 + ((wn4+3)*2+(sl))*512 + l8]; \
        MMSTEP(fa0, fa1, fa2, fa3, fb0, fb1, fb2, fb3) \
    }

#define COMPUTE(bs) CSTEP(bs, 0) CSTEP(bs, 1)

__device__ __forceinline__ void do_tile(
    const short* __restrict__ zt, float* __restrict__ part,
    short* lds, int id, int t)
{
    // Decode linear triangle index -> (bx, by), bx <= by.
    int by = (int)((sqrtf(8.0f * (float)id + 1.0f) - 1.0f) * 0.5f);
    while ((by + 1) * (by + 2) / 2 <= id) ++by;   // fix float rounding
    while (by * (by + 1) / 2 > id) --by;
    int bx = id - by * (by + 1) / 2;

    int w = t >> 6, lane = t & 63;
    int quad = lane >> 4, c16 = lane & 15;
    int wm = w >> 1, wn = w & 1;
    int wm4 = wm * 4, wn4 = wn * 4;
    int l8 = lane * 8;
    int p0 = w * 8;
    int rbase = bx * 128 + wm * 64;
    int jbase = by * 128 + wn * 64;

    const short* stg_base = zt
        + (size_t)((w < 2 ? bx : by) * 8 + (w & 1) * 4) * 4096 + l8;

    f32x4 acc[4][4];
    #pragma unroll
    for (int mt = 0; mt < 4; ++mt)
        #pragma unroll
        for (int nt = 0; nt < 4; ++nt)
            acc[mt][nt] = (f32x4){0.f, 0.f, 0.f, 0.f};

    bf16x8 G0, G1, G2, G3, G4, G5, G6, G7;

    SLD(0)
    DSW(0)
    __syncthreads();
    SLD(1) SB
    COMPUTE(0) SB
    DSW(1)
    __syncthreads();
    SLD(2) SB
    COMPUTE(1) SB
    DSW(0)
    __syncthreads();
    SLD(3) SB
    COMPUTE(0) SB
    DSW(1)
    __syncthreads();
    COMPUTE(1)

    // Epilogue. Row of acc[mt][nt][rg] = rbase+mt*16+quad*4+rg,
    // col = jbase+nt*16+c16.
    float rsum[4][4];
    #pragma unroll
    for (int mt = 0; mt < 4; ++mt)
        #pragma unroll
        for (int rg = 0; rg < 4; ++rg) rsum[mt][rg] = 0.f;

    if (bx == by) {
        #pragma unroll
        for (int mt = 0; mt < 4; ++mt) {
            #pragma unroll
            for (int nt = 0; nt < 4; ++nt) {
                int j = jbase + nt * 16 + c16;
                #pragma unroll
                for (int rg = 0; rg < 4; ++rg) {
                    int r = rbase + mt * 16 + quad * 4 + rg;
                    float e = __expf(2.0f * acc[mt][nt][rg]);
                    rsum[mt][rg] += (r == j) ? 0.f : e;
                }
            }
        }
    } else {
        float csum[4] = {0.f, 0.f, 0.f, 0.f};
        #pragma unroll
        for (int mt = 0; mt < 4; ++mt) {
            #pragma unroll
            for (int nt = 0; nt < 4; ++nt) {
                #pragma unroll
                for (int rg = 0; rg < 4; ++rg) {
                    float e = __expf(2.0f * acc[mt][nt][rg]);
                    rsum[mt][rg] += e;
                    csum[nt] += e;
                }
            }
        }
        #pragma unroll
        for (int nt = 0; nt < 4; ++nt) {
            float v = csum[nt];
            v += __shfl_xor(v, 16, 64);
            v += __shfl_xor(v, 32, 64);
            if (quad == 0)
                part[(size_t)(by * 128 + wn * 64 + nt * 16 + c16) * 64
                     + 2 * bx + wm] = v;
        }
    }

    #pragma unroll
    for (int mt = 0; mt < 4; ++mt) {
        #pragma unroll
        for (int rg = 0; rg < 4; ++rg) {
            float v = rsum[mt][rg];
            v += __shfl_xor(v, 1, 64);
            v += __shfl_xor(v, 2, 64);
            v += __shfl_xor(v, 4, 64);
            v += __shfl_xor(v, 8, 64);
            if (c16 == 0)
                part[(size_t)(rbase + mt * 16 + quad * 4 + rg) * 64
                     + 2 * by + wn] = v;
        }
    }
}

// ---------------------------------------------------------------------------
// Phase 3 (= old redloss_kernel body, bit-identical): virtual block s<32,
// 128 threads. Thread t owns row r = s*128+t; den_r = serial float4 sum of
// its 64 partials; block-reduce; one atomicAdd into out[0].
// ---------------------------------------------------------------------------
__device__ __forceinline__ void do_red(
    const float* __restrict__ part, const float* __restrict__ pos,
    float* __restrict__ out, float* red, int s, int t)
{
    int r = s * 128 + t;
    const float4* p = (const float4*)(part + ((size_t)r << 6));
    float sum = 0.f;
    #pragma unroll
    for (int i = 0; i < 16; ++i) {
        float4 v = p[i];
        sum += v.x + v.y + v.z + v.w;
    }
    float val = logf(sum) - 2.0f * pos[r & (NB - 1)];
    #pragma unroll
    for (int off = 32; off >= 1; off >>= 1) val += __shfl_xor(val, off, 64);
    if ((t & 63) == 0) red[t >> 6] = val;
    __syncthreads();
    if (t == 0)
        atomicAdd(out, (red[0] + red[1]) * (1.0f / (float)TWO_N));
}

// ---------------------------------------------------------------------------
// Fused cooperative kernel: nrm -> grid.sync -> tiles -> grid.sync -> loss.
// ---------------------------------------------------------------------------
__global__ __launch_bounds__(256, 2) void fused_kernel(
    const float* __restrict__ emb_i, const float* __restrict__ emb_j,
    short* __restrict__ zt, float* __restrict__ part,
    float* __restrict__ pos, float* __restrict__ out)
{
    __shared__ short lds[2 * 16384];            // 64 KB -> 2 blocks/CU
    __shared__ float red[2];
    int t = threadIdx.x, bid = blockIdx.x;

    do_nrm(emb_i, emb_j, zt, pos, out, bid, t);

    __threadfence();
    cg::this_grid().sync();

    for (int id = bid; id < NTILES; id += GRID)
        do_tile(zt, part, lds, id, t);

    __threadfence();
    cg::this_grid().sync();

    if (bid < 32 && t < 128)
        do_red(part, pos, out, red, bid, t);
}

// ---------------------------------------------------------------------------
// Fallback standalone kernels (r7 path) if cooperative launch is rejected.
// ---------------------------------------------------------------------------
__global__ __launch_bounds__(256) void nrm_kernel(
    const float* __restrict__ emb_i, const float* __restrict__ emb_j,
    short* __restrict__ zt, float* __restrict__ pos, float* __restrict__ out)
{
    do_nrm(emb_i, emb_j, zt, pos, out, blockIdx.x, threadIdx.x);
}

__global__ __launch_bounds__(256, 2) void simexp_kernel(
    const short* __restrict__ zt, float* __restrict__ part)
{
    __shared__ short lds[2 * 16384];
    do_tile(zt, part, lds, blockIdx.x, threadIdx.x);
}

__global__ __launch_bounds__(128) void redloss_kernel(
    const float* __restrict__ part, const float* __restrict__ pos,
    float* __restrict__ out)
{
    __shared__ float red[2];
    do_red(part, pos, out, red, blockIdx.x, threadIdx.x);
}

// ---------------------------------------------------------------------------
extern "C" void kernel_launch(void* const* d_in, const int* in_sizes, int n_in,
                              void* d_out, int out_size, void* d_ws, size_t ws_size,
                              hipStream_t stream)
{
    const float* emb_i = (const float*)d_in[0];
    const float* emb_j = (const float*)d_in[1];
    float* out = (float*)d_out;

    short* zt = (short*)d_ws;                             // 4096*256 bf16 = 2 MB (tiled)
    float* part = (float*)((char*)d_ws + (size_t)TWO_N * DIM * sizeof(short));
    float* pos = part + (size_t)TWO_N * 64;               // 2048 f32

    void* args[] = { (void*)&emb_i, (void*)&emb_j, (void*)&zt,
                     (void*)&part, (void*)&pos, (void*)&out };
    hipError_t err = hipLaunchCooperativeKernel(
        (const void*)fused_kernel, dim3(GRID), dim3(256), args, 0, stream);

    if (err != hipSuccess) {
        // Fallback: proven r7 three-launch path.
        nrm_kernel<<<NB / 4, 256, 0, stream>>>(emb_i, emb_j, zt, pos, out);
        simexp_kernel<<<NTILES, 256, 0, stream>>>(zt, part);
        redloss_kernel<<<NT1D, 128, 0, stream>>>(part, pos, out);
    }
}

// Round 9
// 108.542 us; speedup vs baseline: 2.6518x; 2.6518x over previous
//
#include <hip/hip_runtime.h>
#include <hip/hip_bf16.h>
#include <math.h>

// Problem constants (reference: BATCH=2048, D=256, TEMP=0.5)
#define NB        2048
#define TWO_N     4096
#define DIM       256
#define EPS       1e-12f
#define NT1D      (TWO_N / 128)                 // 32 tile rows/cols
#define NTILES    (NT1D * (NT1D + 1) / 2)       // 528 upper-triangle tiles

// z storage: FRAGMENT-MAJOR tiled layout (r6). For row R, element e:
//   short_idx = (R>>4)*4096 + (e>>5)*512 + ((e>>3)&3)*128 + (R&15)*8 + (e&7)
// A (row-block RB, K-step s) fragment piece = 1 KB contiguous at
// RB*4096 + s*512; lane l's 16 B at +l*8 shorts.

typedef __attribute__((ext_vector_type(8))) short  bf16x8;   // 8 bf16 = 4 VGPRs
typedef __attribute__((ext_vector_type(4))) float  f32x4;    // MFMA C/D

// ---------------------------------------------------------------------------
// K1: one wave per PAIR r in [0,2048): L2-normalize emb_i[r] -> z[r] and
// emb_j[r] -> z[r+NB] (bf16, fragment-major layout), and write the
// fp32-exact positive dot pos[r] = <z_i, z_j>. Also zeroes the output.
// ---------------------------------------------------------------------------
__global__ __launch_bounds__(256) void nrm_kernel(
    const float* __restrict__ emb_i, const float* __restrict__ emb_j,
    short* __restrict__ zt, float* __restrict__ pos,
    float* __restrict__ out)
{
    int t = threadIdx.x;
    int wave = t >> 6, lane = t & 63;
    int r = blockIdx.x * 4 + wave;              // pair index 0..2047
    float4 a = ((const float4*)(emb_i + (size_t)r * DIM))[lane];
    float4 b = ((const float4*)(emb_j + (size_t)r * DIM))[lane];
    float sa = a.x*a.x + a.y*a.y + a.z*a.z + a.w*a.w;
    float sb = b.x*b.x + b.y*b.y + b.z*b.z + b.w*b.w;
    float sd = a.x*b.x + a.y*b.y + a.z*b.z + a.w*b.w;
    #pragma unroll
    for (int off = 32; off >= 1; off >>= 1) {
        sa += __shfl_xor(sa, off, 64);
        sb += __shfl_xor(sb, off, 64);
        sd += __shfl_xor(sd, off, 64);
    }
    float si = 1.0f / fmaxf(sqrtf(sa), EPS);
    float sj = 1.0f / fmaxf(sqrtf(sb), EPS);

    int dst = (r >> 4) * 4096 + (lane >> 3) * 512 + ((lane >> 1) & 3) * 128
            + (r & 15) * 8 + (lane & 1) * 4;

    union { __hip_bfloat16 h[4]; uint2 u; } pk;
    pk.h[0] = __float2bfloat16(a.x * si);
    pk.h[1] = __float2bfloat16(a.y * si);
    pk.h[2] = __float2bfloat16(a.z * si);
    pk.h[3] = __float2bfloat16(a.w * si);
    *(uint2*)(zt + dst) = pk.u;                       // z_i row r
    pk.h[0] = __float2bfloat16(b.x * sj);
    pk.h[1] = __float2bfloat16(b.y * sj);
    pk.h[2] = __float2bfloat16(b.z * sj);
    pk.h[3] = __float2bfloat16(b.w * sj);
    *(uint2*)(zt + dst + 128 * 4096) = pk.u;          // z_j row r+2048

    if (lane == 0) pos[r] = sd * si * sj;
    if (blockIdx.x == 0 && t == 0) out[0] = 0.0f;     // loss accumulator
}

// ---------------------------------------------------------------------------
// K2: bf16 MFMA over the 528 upper-triangle 128x128 tiles, LDS-STAGED
// (r7 structure, unchanged). IDEMPOTENT: every part[] slot is written
// exactly once per launch with values depending only on zt -> repeated
// launches write identical bytes (used this round for direct timing).
// ---------------------------------------------------------------------------
#define MFMA1(Av, Bv, m, n) \
    acc[m][n] = __builtin_amdgcn_mfma_f32_16x16x32_bf16(Av, Bv, acc[m][n], 0, 0, 0);

#define MFMA_ROW(Av, B0v, B1v, B2v, B3v, m) \
    MFMA1(Av, B0v, m, 0) MFMA1(Av, B1v, m, 1) \
    MFMA1(Av, B2v, m, 2) MFMA1(Av, B3v, m, 3)

#define MMSTEP(A0v, A1v, A2v, A3v, B0v, B1v, B2v, B3v) \
    MFMA_ROW(A0v, B0v, B1v, B2v, B3v, 0) \
    MFMA_ROW(A1v, B0v, B1v, B2v, B3v, 1) \
    MFMA_ROW(A2v, B0v, B1v, B2v, B3v, 2) \
    MFMA_ROW(A3v, B0v, B1v, B2v, B3v, 3)

#define SB __builtin_amdgcn_sched_barrier(0);

#define SLD(c) \
    G0 = *(const bf16x8*)(stg_base + 0 * 4096 + (2*(c)+0) * 512); \
    G1 = *(const bf16x8*)(stg_base + 0 * 4096 + (2*(c)+1) * 512); \
    G2 = *(const bf16x8*)(stg_base + 1 * 4096 + (2*(c)+0) * 512); \
    G3 = *(const bf16x8*)(stg_base + 1 * 4096 + (2*(c)+1) * 512); \
    G4 = *(const bf16x8*)(stg_base + 2 * 4096 + (2*(c)+0) * 512); \
    G5 = *(const bf16x8*)(stg_base + 2 * 4096 + (2*(c)+1) * 512); \
    G6 = *(const bf16x8*)(stg_base + 3 * 4096 + (2*(c)+0) * 512); \
    G7 = *(const bf16x8*)(stg_base + 3 * 4096 + (2*(c)+1) * 512);

#define DSW(bs) \
    *(bf16x8*)&lds[(bs)*16384 + (p0+0)*512 + l8] = G0; \
    *(bf16x8*)&lds[(bs)*16384 + (p0+1)*512 + l8] = G1; \
    *(bf16x8*)&lds[(bs)*16384 + (p0+2)*512 + l8] = G2; \
    *(bf16x8*)&lds[(bs)*16384 + (p0+3)*512 + l8] = G3; \
    *(bf16x8*)&lds[(bs)*16384 + (p0+4)*512 + l8] = G4; \
    *(bf16x8*)&lds[(bs)*16384 + (p0+5)*512 + l8] = G5; \
    *(bf16x8*)&lds[(bs)*16384 + (p0+6)*512 + l8] = G6; \
    *(bf16x8*)&lds[(bs)*16384 + (p0+7)*512 + l8] = G7;

#define CSTEP(bs, sl) \
    { \
        bf16x8 fa0 = *(const bf16x8*)&lds[(bs)*16384 + ((wm4+0)*2+(sl))*512 + l8]; \
        bf16x8 fa1 = *(const bf16x8*)&lds[(bs)*16384 + ((wm4+1)*2+(sl))*512 + l8]; \
        bf16x8 fa2 = *(const bf16x8*)&lds[(bs)*16384 + ((wm4+2)*2+(sl))*512 + l8]; \
        bf16x8 fa3 = *(const bf16x8*)&lds[(bs)*16384 + ((wm4+3)*2+(sl))*512 + l8]; \
        bf16x8 fb0 = *(const bf16x8*)&lds[(bs)*16384 + 8192 + ((wn4+0)*2+(sl))*512 + l8]; \
        bf16x8 fb1 = *(const bf16x8*)&lds[(bs)*16384 + 8192 + ((wn4+1)*2+(sl))*512 + l8]; \
        bf16x8 fb2 = *(const bf16x8*)&lds[(bs)*16384 + 8192 + ((wn4+2)*2+(sl))*512 + l8]; \
        bf16x8 fb3 = *(const bf16x8*)&lds[(bs)*16384 + 8192 + ((wn4+3)*2+(sl))*512 + l8]; \
        MMSTEP(fa0, fa1, fa2, fa3, fb0, fb1, fb2, fb3) \
    }

#define COMPUTE(bs) CSTEP(bs, 0) CSTEP(bs, 1)

__global__ __launch_bounds__(256, 2) void simexp_kernel(
    const short* __restrict__ zt, float* __restrict__ part)
{
    __shared__ short lds[2 * 16384];            // 2 x 32 KB chunk buffers

    // Decode linear triangle index -> (bx, by), bx <= by.
    int id = blockIdx.x;
    int by = (int)((sqrtf(8.0f * (float)id + 1.0f) - 1.0f) * 0.5f);
    while ((by + 1) * (by + 2) / 2 <= id) ++by;   // fix float rounding
    while (by * (by + 1) / 2 > id) --by;
    int bx = id - by * (by + 1) / 2;

    int t = threadIdx.x;
    int w = t >> 6, lane = t & 63;
    int quad = lane >> 4, c16 = lane & 15;
    int wm = w >> 1, wn = w & 1;
    int wm4 = wm * 4, wn4 = wn * 4;
    int l8 = lane * 8;
    int p0 = w * 8;
    int rbase = bx * 128 + wm * 64;
    int jbase = by * 128 + wn * 64;

    const short* stg_base = zt
        + (size_t)((w < 2 ? bx : by) * 8 + (w & 1) * 4) * 4096 + l8;

    f32x4 acc[4][4];
    #pragma unroll
    for (int mt = 0; mt < 4; ++mt)
        #pragma unroll
        for (int nt = 0; nt < 4; ++nt)
            acc[mt][nt] = (f32x4){0.f, 0.f, 0.f, 0.f};

    bf16x8 G0, G1, G2, G3, G4, G5, G6, G7;

    SLD(0)
    DSW(0)
    __syncthreads();
    SLD(1) SB
    COMPUTE(0) SB
    DSW(1)
    __syncthreads();
    SLD(2) SB
    COMPUTE(1) SB
    DSW(0)
    __syncthreads();
    SLD(3) SB
    COMPUTE(0) SB
    DSW(1)
    __syncthreads();
    COMPUTE(1)

    // Epilogue. Row of acc[mt][nt][rg] = rbase+mt*16+quad*4+rg,
    // col = jbase+nt*16+c16.
    float rsum[4][4];
    #pragma unroll
    for (int mt = 0; mt < 4; ++mt)
        #pragma unroll
        for (int rg = 0; rg < 4; ++rg) rsum[mt][rg] = 0.f;

    if (bx == by) {
        #pragma unroll
        for (int mt = 0; mt < 4; ++mt) {
            #pragma unroll
            for (int nt = 0; nt < 4; ++nt) {
                int j = jbase + nt * 16 + c16;
                #pragma unroll
                for (int rg = 0; rg < 4; ++rg) {
                    int r = rbase + mt * 16 + quad * 4 + rg;
                    float e = __expf(2.0f * acc[mt][nt][rg]);
                    rsum[mt][rg] += (r == j) ? 0.f : e;
                }
            }
        }
    } else {
        float csum[4] = {0.f, 0.f, 0.f, 0.f};
        #pragma unroll
        for (int mt = 0; mt < 4; ++mt) {
            #pragma unroll
            for (int nt = 0; nt < 4; ++nt) {
                #pragma unroll
                for (int rg = 0; rg < 4; ++rg) {
                    float e = __expf(2.0f * acc[mt][nt][rg]);
                    rsum[mt][rg] += e;
                    csum[nt] += e;
                }
            }
        }
        #pragma unroll
        for (int nt = 0; nt < 4; ++nt) {
            float v = csum[nt];
            v += __shfl_xor(v, 16, 64);
            v += __shfl_xor(v, 32, 64);
            if (quad == 0)
                part[(size_t)(by * 128 + wn * 64 + nt * 16 + c16) * 64
                     + 2 * bx + wm] = v;
        }
    }

    #pragma unroll
    for (int mt = 0; mt < 4; ++mt) {
        #pragma unroll
        for (int rg = 0; rg < 4; ++rg) {
            float v = rsum[mt][rg];
            v += __shfl_xor(v, 1, 64);
            v += __shfl_xor(v, 2, 64);
            v += __shfl_xor(v, 4, 64);
            v += __shfl_xor(v, 8, 64);
            if (c16 == 0)
                part[(size_t)(rbase + mt * 16 + quad * 4 + rg) * 64
                     + 2 * by + wn] = v;
        }
    }
}

// ---------------------------------------------------------------------------
// K3: 32 blocks x 128 threads. Block s, thread t owns row r = s*128+t:
// den_r = sum of its 64 partials (256 B contiguous), then
// loss_r = log(den_r) - 2*pos[r mod 2048]. Block-reduce, one atomicAdd of
// the scaled partial into out[0] (32 atomics total; out zeroed by K1).
// ---------------------------------------------------------------------------
__global__ __launch_bounds__(128) void redloss_kernel(
    const float* __restrict__ part, const float* __restrict__ pos,
    float* __restrict__ out)
{
    int s = blockIdx.x, t = threadIdx.x;
    int r = s * 128 + t;
    const float4* p = (const float4*)(part + ((size_t)r << 6));
    float sum = 0.f;
    #pragma unroll
    for (int i = 0; i < 16; ++i) {
        float4 v = p[i];
        sum += v.x + v.y + v.z + v.w;
    }
    float val = logf(sum) - 2.0f * pos[r & (NB - 1)];
    #pragma unroll
    for (int off = 32; off >= 1; off >>= 1) val += __shfl_xor(val, off, 64);
    __shared__ float red[2];
    if ((t & 63) == 0) red[t >> 6] = val;
    __syncthreads();
    if (t == 0)
        atomicAdd(out, (red[0] + red[1]) * (1.0f / (float)TWO_N));
}

// ---------------------------------------------------------------------------
// MEASUREMENT ROUND: simexp launched 3x (idempotent). dur_us delta vs the
// single-launch r7 baseline (76.9) gives simexp's true duration:
//   S = (dur - 76.9)/2 - gap.  Ledger A (S~20) -> dur ~117-125;
//   Ledger B (S~6)  -> dur ~89-97.  Next round acts on the answer.
// ---------------------------------------------------------------------------
extern "C" void kernel_launch(void* const* d_in, const int* in_sizes, int n_in,
                              void* d_out, int out_size, void* d_ws, size_t ws_size,
                              hipStream_t stream)
{
    const float* emb_i = (const float*)d_in[0];
    const float* emb_j = (const float*)d_in[1];
    float* out = (float*)d_out;

    short* zt = (short*)d_ws;                             // 4096*256 bf16 = 2 MB (tiled)
    float* part = (float*)((char*)d_ws + (size_t)TWO_N * DIM * sizeof(short));
    float* pos = part + (size_t)TWO_N * 64;               // 2048 f32

    nrm_kernel<<<NB / 4, 256, 0, stream>>>(emb_i, emb_j, zt, pos, out);
    simexp_kernel<<<NTILES, 256, 0, stream>>>(zt, part);
    simexp_kernel<<<NTILES, 256, 0, stream>>>(zt, part);   // idempotent replay #1
    simexp_kernel<<<NTILES, 256, 0, stream>>>(zt, part);   // idempotent replay #2
    redloss_kernel<<<NT1D, 128, 0, stream>>>(part, pos, out);
}

// Round 10
// 74.130 us; speedup vs baseline: 3.8828x; 1.4642x over previous
//
#include <hip/hip_runtime.h>
#include <hip/hip_bf16.h>
#include <math.h>

// Problem constants (reference: BATCH=2048, D=256, TEMP=0.5)
#define NB        2048
#define TWO_N     4096
#define DIM       256
#define EPS       1e-12f
#define NT1D      (TWO_N / 128)                 // 32 tile rows/cols
#define NTILES    (NT1D * (NT1D + 1) / 2)       // 528 upper-triangle tiles

// z storage: FRAGMENT-MAJOR tiled layout (r6). For row R, element e:
//   short_idx = (R>>4)*4096 + (e>>5)*512 + ((e>>3)&3)*128 + (R&15)*8 + (e&7)
// A (row-block RB, K-step s) fragment piece = 1 KB contiguous at
// RB*4096 + s*512; lane l's 16 B at +l*8 shorts.

typedef __attribute__((ext_vector_type(8))) short  bf16x8;   // 8 bf16 = 4 VGPRs
typedef __attribute__((ext_vector_type(4))) float  f32x4;    // MFMA C/D

// ---------------------------------------------------------------------------
// K1: one wave per PAIR r in [0,2048): L2-normalize emb_i[r] -> z[r] and
// emb_j[r] -> z[r+NB] (bf16, fragment-major layout), and write the
// fp32-exact positive dot pos[r] = <z_i, z_j>. Also zeroes the output.
// ---------------------------------------------------------------------------
__global__ __launch_bounds__(256) void nrm_kernel(
    const float* __restrict__ emb_i, const float* __restrict__ emb_j,
    short* __restrict__ zt, float* __restrict__ pos,
    float* __restrict__ out)
{
    int t = threadIdx.x;
    int wave = t >> 6, lane = t & 63;
    int r = blockIdx.x * 4 + wave;              // pair index 0..2047
    float4 a = ((const float4*)(emb_i + (size_t)r * DIM))[lane];
    float4 b = ((const float4*)(emb_j + (size_t)r * DIM))[lane];
    float sa = a.x*a.x + a.y*a.y + a.z*a.z + a.w*a.w;
    float sb = b.x*b.x + b.y*b.y + b.z*b.z + b.w*b.w;
    float sd = a.x*b.x + a.y*b.y + a.z*b.z + a.w*b.w;
    #pragma unroll
    for (int off = 32; off >= 1; off >>= 1) {
        sa += __shfl_xor(sa, off, 64);
        sb += __shfl_xor(sb, off, 64);
        sd += __shfl_xor(sd, off, 64);
    }
    float si = 1.0f / fmaxf(sqrtf(sa), EPS);
    float sj = 1.0f / fmaxf(sqrtf(sb), EPS);

    int dst = (r >> 4) * 4096 + (lane >> 3) * 512 + ((lane >> 1) & 3) * 128
            + (r & 15) * 8 + (lane & 1) * 4;

    union { __hip_bfloat16 h[4]; uint2 u; } pk;
    pk.h[0] = __float2bfloat16(a.x * si);
    pk.h[1] = __float2bfloat16(a.y * si);
    pk.h[2] = __float2bfloat16(a.z * si);
    pk.h[3] = __float2bfloat16(a.w * si);
    *(uint2*)(zt + dst) = pk.u;                       // z_i row r
    pk.h[0] = __float2bfloat16(b.x * sj);
    pk.h[1] = __float2bfloat16(b.y * sj);
    pk.h[2] = __float2bfloat16(b.z * sj);
    pk.h[3] = __float2bfloat16(b.w * sj);
    *(uint2*)(zt + dst + 128 * 4096) = pk.u;          // z_j row r+2048

    if (lane == 0) pos[r] = sd * si * sj;
    if (blockIdx.x == 0 && t == 0) out[0] = 0.0f;     // loss accumulator
}

// ---------------------------------------------------------------------------
// K2: bf16 MFMA over the 528 upper-triangle 128x128 tiles, LDS-STAGED.
// ROUND-10 CHANGE: K-chunk 64 -> 32. Each LDS buffer = 16 KB (A 8 + B 8),
// double-buffered = 32 KB total (was 64 KB). With __launch_bounds__(256,3):
//   - 3 blocks/CU (LDS would allow 5; VGPR cap ~170 binds at 3)
//   - 768 block slots >= 528 blocks -> SINGLE generation, no 2nd-wave tail
//     (r7's 64 KB -> 2 blocks/CU ran 512 + 16-block tail = 2x makespan)
//   - 12 waves/CU of TLP to hide the per-chunk global-load latency that the
//     16-MFMA compute phase can't cover alone.
// 8 chunks of K=32, one barrier per chunk (same proven r7 dbuf discipline).
// Same bytes into the same MFMAs in the same K order -> bit-identical.
// Wave w stages pieces w*4+i (i=0..3): w=0/1 -> A row-blocks 0-3/4-7,
// w=2/3 -> B row-blocks 0-3/4-7. Piece p of chunk buffer b at
// lds[b*8192 + p*512 + lane*8] (A = pieces 0-7, B = pieces 8-15).
// part[] slot scheme unchanged (round-2 comment).
// Fragment layouts (verified m89/m91): A[m=lane&15][k=quad*8+j],
// B[k=quad*8+j][n=lane&15], C/D: col=lane&15, row=quad*4+reg.
// ---------------------------------------------------------------------------
#define MFMA1(Av, Bv, m, n) \
    acc[m][n] = __builtin_amdgcn_mfma_f32_16x16x32_bf16(Av, Bv, acc[m][n], 0, 0, 0);

#define MFMA_ROW(Av, B0v, B1v, B2v, B3v, m) \
    MFMA1(Av, B0v, m, 0) MFMA1(Av, B1v, m, 1) \
    MFMA1(Av, B2v, m, 2) MFMA1(Av, B3v, m, 3)

#define MMSTEP(A0v, A1v, A2v, A3v, B0v, B1v, B2v, B3v) \
    MFMA_ROW(A0v, B0v, B1v, B2v, B3v, 0) \
    MFMA_ROW(A1v, B0v, B1v, B2v, B3v, 1) \
    MFMA_ROW(A2v, B0v, B1v, B2v, B3v, 2) \
    MFMA_ROW(A3v, B0v, B1v, B2v, B3v, 3)

#define SB __builtin_amdgcn_sched_barrier(0);

// Issue the 4 staging loads for chunk c (K-step c) into G0..G3.
#define SLD(c) \
    G0 = *(const bf16x8*)(stg_base + 0 * 4096 + (c) * 512); \
    G1 = *(const bf16x8*)(stg_base + 1 * 4096 + (c) * 512); \
    G2 = *(const bf16x8*)(stg_base + 2 * 4096 + (c) * 512); \
    G3 = *(const bf16x8*)(stg_base + 3 * 4096 + (c) * 512);

// Write G0..G3 to LDS buffer bs (wave's 4 pieces at p0 = w*4).
#define DSW(bs) \
    *(bf16x8*)&lds[(bs)*8192 + (p0+0)*512 + l8] = G0; \
    *(bf16x8*)&lds[(bs)*8192 + (p0+1)*512 + l8] = G1; \
    *(bf16x8*)&lds[(bs)*8192 + (p0+2)*512 + l8] = G2; \
    *(bf16x8*)&lds[(bs)*8192 + (p0+3)*512 + l8] = G3;

// One K-step from chunk buffer bs: 8 ds_read_b128 + 16 MFMA.
#define COMPUTE(bs) \
    { \
        bf16x8 fa0 = *(const bf16x8*)&lds[(bs)*8192 + (wm4+0)*512 + l8]; \
        bf16x8 fa1 = *(const bf16x8*)&lds[(bs)*8192 + (wm4+1)*512 + l8]; \
        bf16x8 fa2 = *(const bf16x8*)&lds[(bs)*8192 + (wm4+2)*512 + l8]; \
        bf16x8 fa3 = *(const bf16x8*)&lds[(bs)*8192 + (wm4+3)*512 + l8]; \
        bf16x8 fb0 = *(const bf16x8*)&lds[(bs)*8192 + 4096 + (wn4+0)*512 + l8]; \
        bf16x8 fb1 = *(const bf16x8*)&lds[(bs)*8192 + 4096 + (wn4+1)*512 + l8]; \
        bf16x8 fb2 = *(const bf16x8*)&lds[(bs)*8192 + 4096 + (wn4+2)*512 + l8]; \
        bf16x8 fb3 = *(const bf16x8*)&lds[(bs)*8192 + 4096 + (wn4+3)*512 + l8]; \
        MMSTEP(fa0, fa1, fa2, fa3, fb0, fb1, fb2, fb3) \
    }

__global__ __launch_bounds__(256, 3) void simexp_kernel(
    const short* __restrict__ zt, float* __restrict__ part)
{
    __shared__ short lds[2 * 8192];             // 2 x 16 KB chunk buffers

    // Decode linear triangle index -> (bx, by), bx <= by.
    int id = blockIdx.x;
    int by = (int)((sqrtf(8.0f * (float)id + 1.0f) - 1.0f) * 0.5f);
    while ((by + 1) * (by + 2) / 2 <= id) ++by;   // fix float rounding
    while (by * (by + 1) / 2 > id) --by;
    int bx = id - by * (by + 1) / 2;

    int t = threadIdx.x;
    int w = t >> 6, lane = t & 63;
    int quad = lane >> 4, c16 = lane & 15;
    int wm = w >> 1, wn = w & 1;
    int wm4 = wm * 4, wn4 = wn * 4;
    int l8 = lane * 8;
    int p0 = w * 4;
    int rbase = bx * 128 + wm * 64;
    int jbase = by * 128 + wn * 64;

    // Staging source: waves 0,1 -> A panel (row-blocks bx*8 + {0-3,4-7});
    // waves 2,3 -> B panel (by*8 + {0-3,4-7}).
    const short* stg_base = zt
        + (size_t)((w < 2 ? bx : by) * 8 + (w & 1) * 4) * 4096 + l8;

    f32x4 acc[4][4];
    #pragma unroll
    for (int mt = 0; mt < 4; ++mt)
        #pragma unroll
        for (int nt = 0; nt < 4; ++nt)
            acc[mt][nt] = (f32x4){0.f, 0.f, 0.f, 0.f};

    bf16x8 G0, G1, G2, G3;

    // Prologue: stage chunk 0 into buf 0.
    SLD(0)
    DSW(0)
    __syncthreads();
    // Chunks 0..6: prefetch c+1 into regs, compute c, write c+1, barrier.
    SLD(1) SB COMPUTE(0) SB DSW(1)
    __syncthreads();
    SLD(2) SB COMPUTE(1) SB DSW(0)
    __syncthreads();
    SLD(3) SB COMPUTE(0) SB DSW(1)
    __syncthreads();
    SLD(4) SB COMPUTE(1) SB DSW(0)
    __syncthreads();
    SLD(5) SB COMPUTE(0) SB DSW(1)
    __syncthreads();
    SLD(6) SB COMPUTE(1) SB DSW(0)
    __syncthreads();
    SLD(7) SB COMPUTE(0) SB DSW(1)
    __syncthreads();
    COMPUTE(1)                                   // chunk 7

    // Epilogue. Row of acc[mt][nt][rg] = rbase+mt*16+quad*4+rg,
    // col = jbase+nt*16+c16.
    float rsum[4][4];
    #pragma unroll
    for (int mt = 0; mt < 4; ++mt)
        #pragma unroll
        for (int rg = 0; rg < 4; ++rg) rsum[mt][rg] = 0.f;

    if (bx == by) {
        #pragma unroll
        for (int mt = 0; mt < 4; ++mt) {
            #pragma unroll
            for (int nt = 0; nt < 4; ++nt) {
                int j = jbase + nt * 16 + c16;
                #pragma unroll
                for (int rg = 0; rg < 4; ++rg) {
                    int r = rbase + mt * 16 + quad * 4 + rg;
                    float e = __expf(2.0f * acc[mt][nt][rg]);
                    rsum[mt][rg] += (r == j) ? 0.f : e;
                }
            }
        }
    } else {
        float csum[4] = {0.f, 0.f, 0.f, 0.f};
        #pragma unroll
        for (int mt = 0; mt < 4; ++mt) {
            #pragma unroll
            for (int nt = 0; nt < 4; ++nt) {
                #pragma unroll
                for (int rg = 0; rg < 4; ++rg) {
                    float e = __expf(2.0f * acc[mt][nt][rg]);
                    rsum[mt][rg] += e;
                    csum[nt] += e;
                }
            }
        }
        #pragma unroll
        for (int nt = 0; nt < 4; ++nt) {
            float v = csum[nt];
            v += __shfl_xor(v, 16, 64);
            v += __shfl_xor(v, 32, 64);
            if (quad == 0)
                part[(size_t)(by * 128 + wn * 64 + nt * 16 + c16) * 64
                     + 2 * bx + wm] = v;
        }
    }

    #pragma unroll
    for (int mt = 0; mt < 4; ++mt) {
        #pragma unroll
        for (int rg = 0; rg < 4; ++rg) {
            float v = rsum[mt][rg];
            v += __shfl_xor(v, 1, 64);
            v += __shfl_xor(v, 2, 64);
            v += __shfl_xor(v, 4, 64);
            v += __shfl_xor(v, 8, 64);
            if (c16 == 0)
                part[(size_t)(rbase + mt * 16 + quad * 4 + rg) * 64
                     + 2 * by + wn] = v;
        }
    }
}

// ---------------------------------------------------------------------------
// K3: 32 blocks x 128 threads. Block s, thread t owns row r = s*128+t:
// den_r = sum of its 64 partials (256 B contiguous), then
// loss_r = log(den_r) - 2*pos[r mod 2048]. Block-reduce, one atomicAdd of
// the scaled partial into out[0] (32 atomics total; out zeroed by K1).
// ---------------------------------------------------------------------------
__global__ __launch_bounds__(128) void redloss_kernel(
    const float* __restrict__ part, const float* __restrict__ pos,
    float* __restrict__ out)
{
    int s = blockIdx.x, t = threadIdx.x;
    int r = s * 128 + t;
    const float4* p = (const float4*)(part + ((size_t)r << 6));
    float sum = 0.f;
    #pragma unroll
    for (int i = 0; i < 16; ++i) {
        float4 v = p[i];
        sum += v.x + v.y + v.z + v.w;
    }
    float val = logf(sum) - 2.0f * pos[r & (NB - 1)];
    #pragma unroll
    for (int off = 32; off >= 1; off >>= 1) val += __shfl_xor(val, off, 64);
    __shared__ float red[2];
    if ((t & 63) == 0) red[t >> 6] = val;
    __syncthreads();
    if (t == 0)
        atomicAdd(out, (red[0] + red[1]) * (1.0f / (float)TWO_N));
}

// ---------------------------------------------------------------------------
extern "C" void kernel_launch(void* const* d_in, const int* in_sizes, int n_in,
                              void* d_out, int out_size, void* d_ws, size_t ws_size,
                              hipStream_t stream)
{
    const float* emb_i = (const float*)d_in[0];
    const float* emb_j = (const float*)d_in[1];
    float* out = (float*)d_out;

    short* zt = (short*)d_ws;                             // 4096*256 bf16 = 2 MB (tiled)
    float* part = (float*)((char*)d_ws + (size_t)TWO_N * DIM * sizeof(short));
    // part: 4096 rows x 64 partials = 1 MB
    float* pos = part + (size_t)TWO_N * 64;               // 2048 f32

    nrm_kernel<<<NB / 4, 256, 0, stream>>>(emb_i, emb_j, zt, pos, out);
    simexp_kernel<<<NTILES, 256, 0, stream>>>(zt, part);
    redloss_kernel<<<NT1D, 128, 0, stream>>>(part, pos, out);
}